// Round 1
// baseline (5826.192 us; speedup 1.0000x reference)
//
#include <hip/hip_runtime.h>
#include <hip/hip_bf16.h>
#include <math.h>

// Problem constants (from reference): B=4, S=1024, D=1024, H=4096, M=16 experts,
// K=2, HEAD_DIM=64 (16 heads), cap = 640, tokens NT = 4096.
#define NTOK   4096
#define DIM    1024
#define H3     3072
#define HMLP   4096
#define NEXP   16
#define CAP    640
#define NHEAD  16
#define HD     64
#define HCHUNK 512   // expert-FFN hidden chunk (8 chunks of 512)

// ---- workspace layout (float offsets) ----
// A region (16,777,216 fl = 64MB): qkv[4096x3072] + v[4096x1024]; later h1[4096x4096]; later expert_in[10240x1024]
#define OFF_A     ((size_t)0)
#define OFF_V     ((size_t)12582912)
#define OFF_B     ((size_t)16777216)   // q, then x1
#define OFF_C     ((size_t)20971520)   // k, then xf (ln2 out)
#define OFF_E     ((size_t)25165824)   // xn (ln1 out), then ao
#define OFF_EOUT  ((size_t)29360128)   // 10240x1024
#define OFF_MID   ((size_t)39845888)   // 10240x512 chunk
#define OFF_PROBS ((size_t)45088768)   // 8192 floats
#define OFF_INDS  ((size_t)45096960)   // 8192 ints
#define OFF_KEEP  ((size_t)45105152)   // 8192 ints
#define OFF_FLAT  ((size_t)45113344)   // 8192 ints
// total = 45,121,536 floats = 180.5 MB

__device__ __forceinline__ float gelu_exact(float x) {
    return 0.5f * x * (1.0f + erff(x * 0.7071067811865475f));
}

// ---------------- LayerNorm: one block per token ----------------
__global__ __launch_bounds__(256) void ln_kernel(const float* __restrict__ x,
                                                 const float* __restrict__ g,
                                                 const float* __restrict__ b,
                                                 float* __restrict__ y) {
    __shared__ float red0[4], red1[4], bc[2];
    const size_t t = blockIdx.x;
    const float* row = x + t * DIM;
    float v[4];
    float s = 0.f, s2 = 0.f;
#pragma unroll
    for (int i = 0; i < 4; i++) {
        float vv = row[threadIdx.x + i * 256];
        v[i] = vv; s += vv; s2 += vv * vv;
    }
#pragma unroll
    for (int off = 32; off > 0; off >>= 1) {
        s  += __shfl_down(s, off);
        s2 += __shfl_down(s2, off);
    }
    const int lane = threadIdx.x & 63, wid = threadIdx.x >> 6;
    if (lane == 0) { red0[wid] = s; red1[wid] = s2; }
    __syncthreads();
    if (threadIdx.x == 0) {
        float S = red0[0] + red0[1] + red0[2] + red0[3];
        float S2 = red1[0] + red1[1] + red1[2] + red1[3];
        float mean = S * (1.0f / DIM);
        float var = S2 * (1.0f / DIM) - mean * mean;
        bc[0] = mean; bc[1] = rsqrtf(var + 1e-5f);
    }
    __syncthreads();
    const float mean = bc[0], r = bc[1];
#pragma unroll
    for (int i = 0; i < 4; i++) {
        int idx = threadIdx.x + i * 256;
        y[t * DIM + idx] = (v[i] - mean) * r * g[idx] + b[idx];
    }
}

// ---------------- NT GEMM: C[n,m] = act(sum_k A[n,k]*B[m,k] + bias[m] + resid[n,m]) ----------------
__global__ __launch_bounds__(256) void gemm_nt(const float* __restrict__ A, int lda,
                                               const float* __restrict__ B, int ldb,
                                               const float* __restrict__ bias,
                                               const float* __restrict__ resid, int ldr,
                                               float* __restrict__ C, int ldc,
                                               int Kdim, int act) {
    __shared__ float As[64][17];
    __shared__ float Bs[64][17];
    const int tid = threadIdx.x;
    const int tx = tid & 15, ty = tid >> 4;
    const int row0 = blockIdx.y * 64, col0 = blockIdx.x * 64;
    const int lrow = tid >> 2;
    const int lk = (tid & 3) * 4;
    float acc[4][4] = {};
    for (int k0 = 0; k0 < Kdim; k0 += 16) {
        const float4 av = *reinterpret_cast<const float4*>(&A[(size_t)(row0 + lrow) * lda + k0 + lk]);
        const float4 bv = *reinterpret_cast<const float4*>(&B[(size_t)(col0 + lrow) * ldb + k0 + lk]);
        __syncthreads();
        As[lrow][lk + 0] = av.x; As[lrow][lk + 1] = av.y; As[lrow][lk + 2] = av.z; As[lrow][lk + 3] = av.w;
        Bs[lrow][lk + 0] = bv.x; Bs[lrow][lk + 1] = bv.y; Bs[lrow][lk + 2] = bv.z; Bs[lrow][lk + 3] = bv.w;
        __syncthreads();
#pragma unroll
        for (int kk = 0; kk < 16; kk++) {
            float a[4], bb[4];
#pragma unroll
            for (int i = 0; i < 4; i++) a[i] = As[ty * 4 + i][kk];
#pragma unroll
            for (int j = 0; j < 4; j++) bb[j] = Bs[tx * 4 + j][kk];
#pragma unroll
            for (int i = 0; i < 4; i++)
#pragma unroll
                for (int j = 0; j < 4; j++)
                    acc[i][j] = fmaf(a[i], bb[j], acc[i][j]);
        }
    }
#pragma unroll
    for (int i = 0; i < 4; i++) {
        const int r = row0 + ty * 4 + i;
#pragma unroll
        for (int j = 0; j < 4; j++) {
            const int c = col0 + tx * 4 + j;
            float v = acc[i][j];
            if (bias) v += bias[c];
            if (resid) v += resid[(size_t)r * ldr + c];
            if (act) v = gelu_exact(v);
            C[(size_t)r * ldc + c] = v;
        }
    }
}

// ---------------- batched NN GEMM: C[m][r,c] (+)= act(sum_k A[m][r,k]*B[m][k,c]) ----------------
__global__ __launch_bounds__(256) void gemm_nn_batched(const float* __restrict__ A, int lda, size_t strideA,
                                                       const float* __restrict__ B, int ldb, size_t strideB,
                                                       float* __restrict__ C, int ldc, size_t strideC,
                                                       int Kdim, int act, int accum) {
    __shared__ float As[64][17];
    __shared__ float Bs[16][68];
    const int m = blockIdx.z;
    A += (size_t)m * strideA;
    B += (size_t)m * strideB;
    C += (size_t)m * strideC;
    const int tid = threadIdx.x;
    const int tx = tid & 15, ty = tid >> 4;
    const int row0 = blockIdx.y * 64, col0 = blockIdx.x * 64;
    const int arow = tid >> 2, ak = (tid & 3) * 4;
    const int bk = tid >> 4, bc4 = (tid & 15) * 4;
    float acc[4][4] = {};
    for (int k0 = 0; k0 < Kdim; k0 += 16) {
        const float4 av = *reinterpret_cast<const float4*>(&A[(size_t)(row0 + arow) * lda + k0 + ak]);
        const float4 bv = *reinterpret_cast<const float4*>(&B[(size_t)(k0 + bk) * ldb + col0 + bc4]);
        __syncthreads();
        As[arow][ak + 0] = av.x; As[arow][ak + 1] = av.y; As[arow][ak + 2] = av.z; As[arow][ak + 3] = av.w;
        Bs[bk][bc4 + 0] = bv.x; Bs[bk][bc4 + 1] = bv.y; Bs[bk][bc4 + 2] = bv.z; Bs[bk][bc4 + 3] = bv.w;
        __syncthreads();
#pragma unroll
        for (int kk = 0; kk < 16; kk++) {
            float a[4], bb[4];
#pragma unroll
            for (int i = 0; i < 4; i++) a[i] = As[ty * 4 + i][kk];
#pragma unroll
            for (int j = 0; j < 4; j++) bb[j] = Bs[kk][tx * 4 + j];
#pragma unroll
            for (int i = 0; i < 4; i++)
#pragma unroll
                for (int j = 0; j < 4; j++)
                    acc[i][j] = fmaf(a[i], bb[j], acc[i][j]);
        }
    }
#pragma unroll
    for (int i = 0; i < 4; i++) {
        const int r = row0 + ty * 4 + i;
#pragma unroll
        for (int j = 0; j < 4; j++) {
            const int c = col0 + tx * 4 + j;
            float v = acc[i][j];
            if (act) v = gelu_exact(v);
            if (accum) v += C[(size_t)r * ldc + c];
            C[(size_t)r * ldc + c] = v;
        }
    }
}

// ---------------- causal flash attention: one thread per query row ----------------
// q,k,v layout: [token, head*64+d] (i.e. [b,s,h,hd]); ao written same layout.
__global__ __launch_bounds__(256) void attn_kernel(const float* __restrict__ q,
                                                   const float* __restrict__ k,
                                                   const float* __restrict__ v,
                                                   float* __restrict__ ao) {
    __shared__ float Ks[32][64];
    __shared__ float Vs[32][64];
    const int bh = blockIdx.y;
    const int b = bh >> 4, h = bh & 15;
    const int qi = blockIdx.x * 256 + threadIdx.x;
    const size_t rowbase = ((size_t)(b * 1024 + qi)) * DIM + h * HD;
    float qr[64], o[64];
#pragma unroll
    for (int d = 0; d < 64; d++) { qr[d] = q[rowbase + d]; o[d] = 0.f; }
    float mx = -1e30f, l = 0.f;
    const int ntiles = blockIdx.x * 8 + 8;
    for (int tile = 0; tile < ntiles; tile++) {
        const int base = tile * 32;
        __syncthreads();
#pragma unroll
        for (int e = 0; e < 8; e++) {
            int idx = threadIdx.x + e * 256;
            int j = idx >> 6, d = idx & 63;
            size_t src = ((size_t)(b * 1024 + base + j)) * DIM + h * HD + d;
            Ks[j][d] = k[src];
            Vs[j][d] = v[src];
        }
        __syncthreads();
        int jmax = qi - base + 1;
        if (jmax > 32) jmax = 32;
        for (int j = 0; j < jmax; j++) {
            float s = 0.f;
#pragma unroll
            for (int d = 0; d < 64; d++) s = fmaf(qr[d], Ks[j][d], s);
            s *= 0.125f;  // 1/sqrt(64)
            float mn = fmaxf(mx, s);
            float c = __expf(mx - mn);
            float p = __expf(s - mn);
            l = l * c + p;
#pragma unroll
            for (int d = 0; d < 64; d++) o[d] = fmaf(o[d], c, p * Vs[j][d]);
            mx = mn;
        }
    }
    const float inv = 1.f / l;
#pragma unroll
    for (int d = 0; d < 64; d++) ao[rowbase + d] = o[d] * inv;
}

// ---------------- router second GEMM (Md=16) + top-2 + softmax probs ----------------
__global__ __launch_bounds__(256) void router2_kernel(const float* __restrict__ h1,
                                                      const float* __restrict__ w2,
                                                      const float* __restrict__ b2,
                                                      float* __restrict__ logits_out,
                                                      float* __restrict__ probs,
                                                      int* __restrict__ inds) {
    __shared__ float red[16][4];
    __shared__ float lg[16];
    const int t = blockIdx.x;
    const float* hrow = h1 + (size_t)t * HMLP;
    float acc[16];
#pragma unroll
    for (int m = 0; m < 16; m++) acc[m] = 0.f;
    for (int i = 0; i < 16; i++) {
        int kk = threadIdx.x + i * 256;
        float hv = hrow[kk];
#pragma unroll
        for (int m = 0; m < 16; m++) acc[m] = fmaf(hv, w2[m * HMLP + kk], acc[m]);
    }
#pragma unroll
    for (int m = 0; m < 16; m++)
#pragma unroll
        for (int off = 32; off > 0; off >>= 1) acc[m] += __shfl_down(acc[m], off);
    const int lane = threadIdx.x & 63, wid = threadIdx.x >> 6;
    if (lane == 0) {
#pragma unroll
        for (int m = 0; m < 16; m++) red[m][wid] = acc[m];
    }
    __syncthreads();
    if (threadIdx.x < 16) {
        float v = red[threadIdx.x][0] + red[threadIdx.x][1] + red[threadIdx.x][2] + red[threadIdx.x][3]
                  + b2[threadIdx.x];
        lg[threadIdx.x] = v;
        logits_out[(size_t)t * 16 + threadIdx.x] = v;
    }
    __syncthreads();
    if (threadIdx.x == 0) {
        int i0 = 0; float v0 = lg[0];
        for (int m = 1; m < 16; m++) if (lg[m] > v0) { v0 = lg[m]; i0 = m; }
        int i1 = -1; float v1 = -3.4e38f;
        for (int m = 0; m < 16; m++) if (m != i0 && lg[m] > v1) { v1 = lg[m]; i1 = m; }
        float e1 = expf(v1 - v0);
        float den = 1.f + e1;
        inds[2 * t] = i0; inds[2 * t + 1] = i1;
        probs[2 * t] = 1.f / den; probs[2 * t + 1] = e1 / den;
    }
}

// ---------------- capacity scan (sequential cumsum semantics), single block ----------------
__global__ __launch_bounds__(256) void scan_kernel(const int* __restrict__ inds,
                                                   int* __restrict__ keep,
                                                   int* __restrict__ flat) {
    __shared__ int counts[256][16];
    const int t = threadIdx.x;
#pragma unroll
    for (int e = 0; e < 16; e++) counts[t][e] = 0;
    const int base = t * 32;
    for (int i = 0; i < 32; i++) counts[t][inds[base + i]]++;
    __syncthreads();
    if (t < 16) {
        int run = 0;
        for (int c = 0; c < 256; c++) { int tmp = counts[c][t]; counts[c][t] = run; run += tmp; }
    }
    __syncthreads();
    for (int i = 0; i < 32; i++) {
        int e = inds[base + i];
        int p = counts[t][e]++;
        keep[base + i] = (p < CAP) ? 1 : 0;
        flat[base + i] = e * CAP + p;
    }
}

// ---------------- scatter tokens into expert buffers ----------------
__global__ __launch_bounds__(256) void scatter_kernel(const float* __restrict__ xf,
                                                      const int* __restrict__ keep,
                                                      const int* __restrict__ flat,
                                                      float* __restrict__ expert_in) {
    const int e = blockIdx.x;
    if (!keep[e]) return;
    const int token = e >> 1;
    const float* src = xf + (size_t)token * DIM;
    float* dst = expert_in + (size_t)flat[e] * DIM;
#pragma unroll
    for (int i = 0; i < 4; i++) dst[threadIdx.x + i * 256] = src[threadIdx.x + i * 256];
}

// ---------------- combine: out = x1 + (kept ? sum p_k * eout : xf) ----------------
__global__ __launch_bounds__(256) void combine_kernel(const float* __restrict__ x1,
                                                      const float* __restrict__ xf,
                                                      const float* __restrict__ eout,
                                                      const float* __restrict__ probs,
                                                      const int* __restrict__ keep,
                                                      const int* __restrict__ flat,
                                                      float* __restrict__ out) {
    const int t = blockIdx.x;
    const int k0 = keep[2 * t], k1 = keep[2 * t + 1];
    const float p0 = probs[2 * t], p1 = probs[2 * t + 1];
    const size_t f0 = (size_t)flat[2 * t] * DIM, f1 = (size_t)flat[2 * t + 1] * DIM;
    const bool has = (k0 || k1);
    const size_t base = (size_t)t * DIM;
#pragma unroll
    for (int i = 0; i < 4; i++) {
        const int idx = threadIdx.x + i * 256;
        float mo;
        if (has) {
            mo = 0.f;
            if (k0) mo += p0 * eout[f0 + idx];
            if (k1) mo += p1 * eout[f1 + idx];
        } else {
            mo = xf[base + idx];
        }
        out[base + idx] = x1[base + idx] + mo;
    }
}

extern "C" void kernel_launch(void* const* d_in, const int* in_sizes, int n_in,
                              void* d_out, int out_size, void* d_ws, size_t ws_size,
                              hipStream_t stream) {
    const float* x          = (const float*)d_in[0];
    const float* ln1_g      = (const float*)d_in[1];
    const float* ln1_b      = (const float*)d_in[2];
    const float* qkv_w      = (const float*)d_in[3];
    const float* qkv_b      = (const float*)d_in[4];
    const float* attn_in_w  = (const float*)d_in[5];
    const float* attn_in_b  = (const float*)d_in[6];
    const float* attn_out_w = (const float*)d_in[7];
    const float* attn_out_b = (const float*)d_in[8];
    const float* ln2_g      = (const float*)d_in[9];
    const float* ln2_b      = (const float*)d_in[10];
    const float* r_w1       = (const float*)d_in[11];
    const float* r_b1       = (const float*)d_in[12];
    const float* r_w2       = (const float*)d_in[13];
    const float* r_b2       = (const float*)d_in[14];
    const float* mlp1       = (const float*)d_in[15];
    const float* mlp2       = (const float*)d_in[16];

    float* ws = (float*)d_ws;
    float* qkv       = ws + OFF_A;
    float* vbuf      = ws + OFF_V;
    float* qbuf      = ws + OFF_B;
    float* kbuf      = ws + OFF_C;
    float* xn        = ws + OFF_E;
    float* ao        = ws + OFF_E;
    float* x1        = ws + OFF_B;
    float* xf        = ws + OFF_C;
    float* h1        = ws + OFF_A;
    float* expert_in = ws + OFF_A;
    float* eout      = ws + OFF_EOUT;
    float* mid       = ws + OFF_MID;
    float* probs     = ws + OFF_PROBS;
    int*   inds      = (int*)(ws + OFF_INDS);
    int*   keep      = (int*)(ws + OFF_KEEP);
    int*   flat      = (int*)(ws + OFF_FLAT);

    float* out        = (float*)d_out;
    float* logits_out = out + (size_t)NTOK * DIM;  // second tuple output

    // 1. LN1
    ln_kernel<<<NTOK, 256, 0, stream>>>(x, ln1_g, ln1_b, xn);
    // 2. qkv = xn @ qkv_w.T + qkv_b   [4096, 3072]
    gemm_nt<<<dim3(H3 / 64, NTOK / 64), 256, 0, stream>>>(xn, DIM, qkv_w, DIM, qkv_b,
                                                          nullptr, 0, qkv, H3, DIM, 0);
    // 3. q/k/v in-projections [4096, 1024] each
    gemm_nt<<<dim3(DIM / 64, NTOK / 64), 256, 0, stream>>>(qkv + 0, H3, attn_in_w + 0, DIM,
                                                           attn_in_b + 0, nullptr, 0, qbuf, DIM, DIM, 0);
    gemm_nt<<<dim3(DIM / 64, NTOK / 64), 256, 0, stream>>>(qkv + 1024, H3, attn_in_w + (size_t)1024 * DIM, DIM,
                                                           attn_in_b + 1024, nullptr, 0, kbuf, DIM, DIM, 0);
    gemm_nt<<<dim3(DIM / 64, NTOK / 64), 256, 0, stream>>>(qkv + 2048, H3, attn_in_w + (size_t)2048 * DIM, DIM,
                                                           attn_in_b + 2048, nullptr, 0, vbuf, DIM, DIM, 0);
    // 4. attention -> ao (reuses xn region; xn dead after step 2)
    attn_kernel<<<dim3(4, 64), 256, 0, stream>>>(qbuf, kbuf, vbuf, ao);
    // 5. x1 = x + ao @ attn_out_w.T + b
    gemm_nt<<<dim3(DIM / 64, NTOK / 64), 256, 0, stream>>>(ao, DIM, attn_out_w, DIM, attn_out_b,
                                                           x, DIM, x1, DIM, DIM, 0);
    // 6. LN2
    ln_kernel<<<NTOK, 256, 0, stream>>>(x1, ln2_g, ln2_b, xf);
    // 7. h1 = gelu(xf @ r_w1.T + r_b1)  [4096, 4096]
    gemm_nt<<<dim3(HMLP / 64, NTOK / 64), 256, 0, stream>>>(xf, DIM, r_w1, DIM, r_b1,
                                                            nullptr, 0, h1, HMLP, DIM, 1);
    // 8. logits + top-2 + probs
    router2_kernel<<<NTOK, 256, 0, stream>>>(h1, r_w2, r_b2, logits_out, probs, inds);
    // 9. capacity scan
    scan_kernel<<<1, 256, 0, stream>>>(inds, keep, flat);
    // 10. scatter into expert buffers (h1 dead; region A reused)
    scatter_kernel<<<NTOK * 2, 256, 0, stream>>>(xf, keep, flat, expert_in);
    // 11. grouped expert FFN, H chunked by 512, accumulate eout
    for (int c = 0; c < HMLP / HCHUNK; c++) {
        const int h0 = c * HCHUNK;
        gemm_nn_batched<<<dim3(HCHUNK / 64, CAP / 64, NEXP), 256, 0, stream>>>(
            expert_in, DIM, (size_t)CAP * DIM,
            mlp1 + h0, HMLP, (size_t)DIM * HMLP,
            mid, HCHUNK, (size_t)CAP * HCHUNK,
            DIM, 1 /*gelu*/, 0);
        gemm_nn_batched<<<dim3(DIM / 64, CAP / 64, NEXP), 256, 0, stream>>>(
            mid, HCHUNK, (size_t)CAP * HCHUNK,
            mlp2 + (size_t)h0 * DIM, DIM, (size_t)HMLP * DIM,
            eout, DIM, (size_t)CAP * DIM,
            HCHUNK, 0, c > 0 /*accumulate after first chunk*/);
    }
    // 12. combine + residual, write final output
    combine_kernel<<<NTOK, 256, 0, stream>>>(x1, xf, eout, probs, keep, flat, out);
}

// Round 3
// 2760.065 us; speedup vs baseline: 2.1109x; 2.1109x over previous
//
#include <hip/hip_runtime.h>
#include <math.h>

#define NTOK   4096
#define DIM    1024
#define H3     3072
#define HMLP   4096
#define NEXP   16
#define CAP    640
#define HCHUNK 1024
#define LSCALE 2048.0f
#define INV_LSCALE (1.0f / 2048.0f)

typedef _Float16 half8 __attribute__((ext_vector_type(8)));
typedef __attribute__((ext_vector_type(4))) float floatx4;

// ---- workspace layout (float-element offsets) ----
#define F_QKV_HI   ((size_t)0)
#define F_QKV_LO   ((size_t)6291456)
#define F_XN_HI    ((size_t)12582912)
#define F_XN_LO    ((size_t)14680064)
#define F_H1       ((size_t)0)
#define F_EOUT     ((size_t)0)
#define F_QBUF     ((size_t)16777216)
#define F_KBUF     ((size_t)20971520)
#define F_VBUF     ((size_t)25165824)
#define F_AO_HI    ((size_t)29360128)
#define F_AO_LO    ((size_t)31457280)
#define F_XF_HI    ((size_t)33554432)
#define F_XF_LO    ((size_t)35651584)
#define F_WQKV_HI  ((size_t)37748736)
#define F_WQKV_LO  ((size_t)39321600)
#define F_WAIN_HI  ((size_t)40894464)
#define F_WAIN_LO  ((size_t)42467328)
#define F_WAOUT_HI ((size_t)44040192)
#define F_WAOUT_LO ((size_t)44564480)
#define F_WR1_HI   ((size_t)45088768)
#define F_WR1_LO   ((size_t)47185920)
// phase3 overlay (phase1/2 contents dead)
#define F_EXPIN    ((size_t)16777216)
#define F_MLP1T    ((size_t)22020096)
#define F_MID      ((size_t)30408704)
#define F_MLP2T    ((size_t)35651584)
// persistent
#define F_X1       ((size_t)49283072)
#define F_XF       ((size_t)53477376)
#define F_PROBS    ((size_t)57671680)
#define F_INDS     ((size_t)57679872)
#define F_KEEP     ((size_t)57688064)
#define F_FLAT     ((size_t)57696256)

__device__ __forceinline__ ushort f2h(float f) {
    _Float16 h = (_Float16)f;
    union { _Float16 h; ushort u; } c; c.h = h; return c.u;
}
__device__ __forceinline__ float h2f(ushort u) {
    union { ushort u; _Float16 h; } c; c.u = u; return (float)c.h;
}
__device__ __forceinline__ float gelu_exact(float x) {
    return 0.5f * x * (1.0f + erff(x * 0.7071067811865475f));
}

// ---------------- split fp32 -> (hi fp16, lo fp16 scaled by 2048) ----------------
__global__ __launch_bounds__(256) void split_f32(const float* __restrict__ x,
                                                 ushort* __restrict__ hi,
                                                 ushort* __restrict__ lo, int n4) {
    int i = blockIdx.x * 256 + threadIdx.x;
    if (i >= n4) return;
    float4 v = ((const float4*)x)[i];
    float vv[4] = {v.x, v.y, v.z, v.w};
    ushort h[4], l[4];
#pragma unroll
    for (int e = 0; e < 4; e++) {
        h[e] = f2h(vv[e]);
        l[e] = f2h((vv[e] - h2f(h[e])) * LSCALE);
    }
    ((ushort4*)hi)[i] = make_ushort4(h[0], h[1], h[2], h[3]);
    ((ushort4*)lo)[i] = make_ushort4(l[0], l[1], l[2], l[3]);
}

// ---------------- LayerNorm: optional fp32 / fp16-hi / fp16-lo outputs ----------------
__global__ __launch_bounds__(256) void ln_kernel(const float* __restrict__ x,
                                                 const float* __restrict__ g,
                                                 const float* __restrict__ b,
                                                 float* __restrict__ yf,
                                                 ushort* __restrict__ yhi,
                                                 ushort* __restrict__ ylo) {
    __shared__ float red0[4], red1[4], bc[2];
    const size_t t = blockIdx.x;
    const float* row = x + t * DIM;
    float v[4];
    float s = 0.f, s2 = 0.f;
#pragma unroll
    for (int i = 0; i < 4; i++) {
        float vv = row[threadIdx.x + i * 256];
        v[i] = vv; s += vv; s2 += vv * vv;
    }
#pragma unroll
    for (int off = 32; off > 0; off >>= 1) {
        s  += __shfl_down(s, off);
        s2 += __shfl_down(s2, off);
    }
    const int lane = threadIdx.x & 63, wid = threadIdx.x >> 6;
    if (lane == 0) { red0[wid] = s; red1[wid] = s2; }
    __syncthreads();
    if (threadIdx.x == 0) {
        float S = red0[0] + red0[1] + red0[2] + red0[3];
        float S2 = red1[0] + red1[1] + red1[2] + red1[3];
        float mean = S * (1.0f / DIM);
        float var = S2 * (1.0f / DIM) - mean * mean;
        bc[0] = mean; bc[1] = rsqrtf(var + 1e-5f);
    }
    __syncthreads();
    const float mean = bc[0], r = bc[1];
#pragma unroll
    for (int i = 0; i < 4; i++) {
        int idx = threadIdx.x + i * 256;
        float val = (v[i] - mean) * r * g[idx] + b[idx];
        size_t o = t * DIM + idx;
        if (yf) yf[o] = val;
        if (yhi) {
            ushort h = f2h(val);
            yhi[o] = h;
            if (ylo) ylo[o] = f2h((val - h2f(h)) * LSCALE);
        }
    }
}

// ---------------- fp16 MFMA NT GEMM; SPLIT = scaled hi/lo (fp32-accurate) ----------------
// C = act( A@B.T + bias + resid (+ C_prev) );  SPLIT: A=Ah+Al/2048, B=Bh+Bl/2048,
// computes Ah*Bh (acc) + Ah*Bl + Al*Bh (acc2, scaled 2048x), recombined at epilogue.
template<bool SPLIT>
__global__ __launch_bounds__(256) void gemm_ht(
    const ushort* __restrict__ Ahi, const ushort* __restrict__ Alo, int lda, long long sA,
    const ushort* __restrict__ Bhi, const ushort* __restrict__ Blo, int ldb, long long sB,
    const float* __restrict__ bias, long long sBias,
    const float* __restrict__ resid, int ldr,
    float* __restrict__ outf, ushort* __restrict__ outhi, ushort* __restrict__ outlo,
    int ldc, long long sC, int Kdim, int act, int accum) {
    __shared__ ushort sAh[128][40];
    __shared__ ushort sBh[128][40];
    __shared__ ushort sAl[SPLIT ? 128 : 1][40];
    __shared__ ushort sBl[SPLIT ? 128 : 1][40];
    const int z = blockIdx.z;
    Ahi += (size_t)z * sA; Bhi += (size_t)z * sB;
    if constexpr (SPLIT) { Alo += (size_t)z * sA; Blo += (size_t)z * sB; }
    if (bias) bias += (size_t)z * sBias;
    if (outf) outf += (size_t)z * sC;
    if (outhi) outhi += (size_t)z * sC;
    if (outlo) outlo += (size_t)z * sC;

    const int tid = threadIdx.x;
    const int row0 = blockIdx.y * 128, col0 = blockIdx.x * 128;
    const int sr = tid >> 2, skq = (tid & 3) * 8;
    const int lane = tid & 63;
    const int m = lane & 15, half = lane >> 4;
    const int w = tid >> 6;
    const int ar0 = (w >> 1) * 64, bc0 = (w & 1) * 64;

    floatx4 acc[4][4];
    floatx4 acc2[SPLIT ? 4 : 1][SPLIT ? 4 : 1];
#pragma unroll
    for (int i = 0; i < 4; i++)
#pragma unroll
        for (int j = 0; j < 4; j++) acc[i][j] = (floatx4){0.f, 0.f, 0.f, 0.f};
    if constexpr (SPLIT) {
#pragma unroll
        for (int i = 0; i < 4; i++)
#pragma unroll
            for (int j = 0; j < 4; j++) acc2[i][j] = (floatx4){0.f, 0.f, 0.f, 0.f};
    }

    for (int k0 = 0; k0 < Kdim; k0 += 32) {
        uint4 a0 = *(const uint4*)(Ahi + (size_t)(row0 + sr) * lda + k0 + skq);
        uint4 a1 = *(const uint4*)(Ahi + (size_t)(row0 + sr + 64) * lda + k0 + skq);
        uint4 b0 = *(const uint4*)(Bhi + (size_t)(col0 + sr) * ldb + k0 + skq);
        uint4 b1 = *(const uint4*)(Bhi + (size_t)(col0 + sr + 64) * ldb + k0 + skq);
        uint4 a2, a3, b2, b3;
        if constexpr (SPLIT) {
            a2 = *(const uint4*)(Alo + (size_t)(row0 + sr) * lda + k0 + skq);
            a3 = *(const uint4*)(Alo + (size_t)(row0 + sr + 64) * lda + k0 + skq);
            b2 = *(const uint4*)(Blo + (size_t)(col0 + sr) * ldb + k0 + skq);
            b3 = *(const uint4*)(Blo + (size_t)(col0 + sr + 64) * ldb + k0 + skq);
        }
        __syncthreads();
        *(uint4*)&sAh[sr][skq] = a0;
        *(uint4*)&sAh[sr + 64][skq] = a1;
        *(uint4*)&sBh[sr][skq] = b0;
        *(uint4*)&sBh[sr + 64][skq] = b1;
        if constexpr (SPLIT) {
            *(uint4*)&sAl[sr][skq] = a2;
            *(uint4*)&sAl[sr + 64][skq] = a3;
            *(uint4*)&sBl[sr][skq] = b2;
            *(uint4*)&sBl[sr + 64][skq] = b3;
        }
        __syncthreads();
        half8 fa[4], fb[4], fal[4], fbl[4];
#pragma unroll
        for (int i = 0; i < 4; i++) fa[i] = *(const half8*)&sAh[ar0 + i * 16 + m][half * 8];
#pragma unroll
        for (int j = 0; j < 4; j++) fb[j] = *(const half8*)&sBh[bc0 + j * 16 + m][half * 8];
        if constexpr (SPLIT) {
#pragma unroll
            for (int i = 0; i < 4; i++) fal[i] = *(const half8*)&sAl[ar0 + i * 16 + m][half * 8];
#pragma unroll
            for (int j = 0; j < 4; j++) fbl[j] = *(const half8*)&sBl[bc0 + j * 16 + m][half * 8];
        }
#pragma unroll
        for (int i = 0; i < 4; i++)
#pragma unroll
            for (int j = 0; j < 4; j++) {
                acc[i][j] = __builtin_amdgcn_mfma_f32_16x16x32_f16(fa[i], fb[j], acc[i][j], 0, 0, 0);
                if constexpr (SPLIT) {
                    acc2[i][j] = __builtin_amdgcn_mfma_f32_16x16x32_f16(fa[i], fbl[j], acc2[i][j], 0, 0, 0);
                    acc2[i][j] = __builtin_amdgcn_mfma_f32_16x16x32_f16(fal[i], fb[j], acc2[i][j], 0, 0, 0);
                }
            }
    }
    // epilogue: C/D layout col=lane&15, row=(lane>>4)*4+reg
#pragma unroll
    for (int i = 0; i < 4; i++) {
#pragma unroll
        for (int j = 0; j < 4; j++) {
            const int col = col0 + bc0 + j * 16 + m;
            const float bv = bias ? bias[col] : 0.f;
#pragma unroll
            for (int r = 0; r < 4; r++) {
                const int row = row0 + ar0 + i * 16 + half * 4 + r;
                float v = acc[i][j][r];
                if constexpr (SPLIT) v += acc2[i][j][r] * INV_LSCALE;
                v += bv;
                if (resid) v += resid[(size_t)row * ldr + col];
                if (accum) v += outf[(size_t)row * ldc + col];
                if (act) v = gelu_exact(v);
                const size_t o = (size_t)row * ldc + col;
                if (outf) outf[o] = v;
                if (outhi) {
                    ushort h = f2h(v);
                    outhi[o] = h;
                    if (outlo) outlo[o] = f2h((v - h2f(h)) * LSCALE);
                }
            }
        }
    }
}

// ---------------- transpose fp32 [R,C] -> fp16 [C,R], batched ----------------
__global__ __launch_bounds__(256) void transpose_h(const float* __restrict__ in, long long sIn, int ldin,
                                                   ushort* __restrict__ out, long long sOut, int ldout) {
    __shared__ float t[32][33];
    const int z = blockIdx.z;
    in += (size_t)z * sIn; out += (size_t)z * sOut;
    const int cx = threadIdx.x & 31, ry = threadIdx.x >> 5;
    const int r0 = blockIdx.y * 32, c0 = blockIdx.x * 32;
#pragma unroll
    for (int rr = 0; rr < 4; rr++)
        t[ry + rr * 8][cx] = in[(size_t)(r0 + ry + rr * 8) * ldin + c0 + cx];
    __syncthreads();
#pragma unroll
    for (int rr = 0; rr < 4; rr++)
        out[(size_t)(c0 + ry + rr * 8) * ldout + r0 + cx] = f2h(t[cx][ry + rr * 8]);
}

// ---------------- causal flash attention (fp32), writes fp16 hi/lo ----------------
__global__ __launch_bounds__(256) void attn_kernel(const float* __restrict__ q,
                                                   const float* __restrict__ k,
                                                   const float* __restrict__ v,
                                                   ushort* __restrict__ ao_hi,
                                                   ushort* __restrict__ ao_lo) {
    __shared__ float Ks[32][64];
    __shared__ float Vs[32][64];
    const int bh = blockIdx.y;
    const int b = bh >> 4, h = bh & 15;
    const int qi = blockIdx.x * 256 + threadIdx.x;
    const size_t rowbase = ((size_t)(b * 1024 + qi)) * DIM + h * 64;
    float qr[64], o[64];
#pragma unroll
    for (int d = 0; d < 64; d++) { qr[d] = q[rowbase + d]; o[d] = 0.f; }
    float mx = -1e30f, l = 0.f;
    const int ntiles = blockIdx.x * 8 + 8;
    for (int tile = 0; tile < ntiles; tile++) {
        const int base = tile * 32;
        __syncthreads();
#pragma unroll
        for (int e = 0; e < 8; e++) {
            int idx = threadIdx.x + e * 256;
            int j = idx >> 6, d = idx & 63;
            size_t src = ((size_t)(b * 1024 + base + j)) * DIM + h * 64 + d;
            Ks[j][d] = k[src];
            Vs[j][d] = v[src];
        }
        __syncthreads();
        int jmax = qi - base + 1;
        if (jmax > 32) jmax = 32;
        for (int j = 0; j < jmax; j++) {
            float s = 0.f;
#pragma unroll
            for (int d = 0; d < 64; d++) s = fmaf(qr[d], Ks[j][d], s);
            s *= 0.125f;
            float mn = fmaxf(mx, s);
            float c = __expf(mx - mn);
            float p = __expf(s - mn);
            l = l * c + p;
#pragma unroll
            for (int d = 0; d < 64; d++) o[d] = fmaf(o[d], c, p * Vs[j][d]);
            mx = mn;
        }
    }
    const float inv = 1.f / l;
#pragma unroll
    for (int d = 0; d < 64; d++) {
        float val = o[d] * inv;
        ushort h16 = f2h(val);
        ao_hi[rowbase + d] = h16;
        ao_lo[rowbase + d] = f2h((val - h2f(h16)) * LSCALE);
    }
}

// ---------------- router second GEMM + top-2 + softmax probs (pure fp32) ----------------
__global__ __launch_bounds__(256) void router2_kernel(const float* __restrict__ h1,
                                                      const float* __restrict__ w2,
                                                      const float* __restrict__ b2,
                                                      float* __restrict__ logits_out,
                                                      float* __restrict__ probs,
                                                      int* __restrict__ inds) {
    __shared__ float red[16][4];
    __shared__ float lg[16];
    const int t = blockIdx.x;
    const float* hrow = h1 + (size_t)t * HMLP;
    float acc[16];
#pragma unroll
    for (int m = 0; m < 16; m++) acc[m] = 0.f;
    for (int i = 0; i < 16; i++) {
        int kk = threadIdx.x + i * 256;
        float hv = hrow[kk];
#pragma unroll
        for (int m = 0; m < 16; m++) acc[m] = fmaf(hv, w2[m * HMLP + kk], acc[m]);
    }
#pragma unroll
    for (int m = 0; m < 16; m++)
#pragma unroll
        for (int off = 32; off > 0; off >>= 1) acc[m] += __shfl_down(acc[m], off);
    const int lane = threadIdx.x & 63, wid = threadIdx.x >> 6;
    if (lane == 0) {
#pragma unroll
        for (int m = 0; m < 16; m++) red[m][wid] = acc[m];
    }
    __syncthreads();
    if (threadIdx.x < 16) {
        float v = red[threadIdx.x][0] + red[threadIdx.x][1] + red[threadIdx.x][2] + red[threadIdx.x][3]
                  + b2[threadIdx.x];
        lg[threadIdx.x] = v;
        logits_out[(size_t)t * 16 + threadIdx.x] = v;
    }
    __syncthreads();
    if (threadIdx.x == 0) {
        int i0 = 0; float v0 = lg[0];
        for (int m = 1; m < 16; m++) if (lg[m] > v0) { v0 = lg[m]; i0 = m; }
        int i1 = -1; float v1 = -3.4e38f;
        for (int m = 0; m < 16; m++) if (m != i0 && lg[m] > v1) { v1 = lg[m]; i1 = m; }
        float e1 = expf(v1 - v0);
        float den = 1.f + e1;
        inds[2 * t] = i0; inds[2 * t + 1] = i1;
        probs[2 * t] = 1.f / den; probs[2 * t + 1] = e1 / den;
    }
}

// ---------------- capacity scan ----------------
__global__ __launch_bounds__(256) void scan_kernel(const int* __restrict__ inds,
                                                   int* __restrict__ keep,
                                                   int* __restrict__ flat) {
    __shared__ int counts[256][16];
    const int t = threadIdx.x;
#pragma unroll
    for (int e = 0; e < 16; e++) counts[t][e] = 0;
    const int base = t * 32;
    for (int i = 0; i < 32; i++) counts[t][inds[base + i]]++;
    __syncthreads();
    if (t < 16) {
        int run = 0;
        for (int c = 0; c < 256; c++) { int tmp = counts[c][t]; counts[c][t] = run; run += tmp; }
    }
    __syncthreads();
    for (int i = 0; i < 32; i++) {
        int e = inds[base + i];
        int p = counts[t][e]++;
        keep[base + i] = (p < CAP) ? 1 : 0;
        flat[base + i] = e * CAP + p;
    }
}

// ---------------- scatter tokens (fp32 xf -> fp16 expert_in) ----------------
__global__ __launch_bounds__(256) void scatter_kernel(const float* __restrict__ xf,
                                                      const int* __restrict__ keep,
                                                      const int* __restrict__ flat,
                                                      ushort* __restrict__ expert_in) {
    const int e = blockIdx.x;
    if (!keep[e]) return;
    const int token = e >> 1;
    const float* src = xf + (size_t)token * DIM;
    ushort* dst = expert_in + (size_t)flat[e] * DIM;
#pragma unroll
    for (int i = 0; i < 4; i++) dst[threadIdx.x + i * 256] = f2h(src[threadIdx.x + i * 256]);
}

// ---------------- combine ----------------
__global__ __launch_bounds__(256) void combine_kernel(const float* __restrict__ x1,
                                                      const float* __restrict__ xf,
                                                      const float* __restrict__ eout,
                                                      const float* __restrict__ probs,
                                                      const int* __restrict__ keep,
                                                      const int* __restrict__ flat,
                                                      float* __restrict__ out) {
    const int t = blockIdx.x;
    const int k0 = keep[2 * t], k1 = keep[2 * t + 1];
    const float p0 = probs[2 * t], p1 = probs[2 * t + 1];
    const size_t f0 = (size_t)flat[2 * t] * DIM, f1 = (size_t)flat[2 * t + 1] * DIM;
    const bool has = (k0 || k1);
    const size_t base = (size_t)t * DIM;
#pragma unroll
    for (int i = 0; i < 4; i++) {
        const int idx = threadIdx.x + i * 256;
        float mo;
        if (has) {
            mo = 0.f;
            if (k0) mo += p0 * eout[f0 + idx];
            if (k1) mo += p1 * eout[f1 + idx];
        } else {
            mo = xf[base + idx];
        }
        out[base + idx] = x1[base + idx] + mo;
    }
}

extern "C" void kernel_launch(void* const* d_in, const int* in_sizes, int n_in,
                              void* d_out, int out_size, void* d_ws, size_t ws_size,
                              hipStream_t stream) {
    const float* x          = (const float*)d_in[0];
    const float* ln1_g      = (const float*)d_in[1];
    const float* ln1_b      = (const float*)d_in[2];
    const float* qkv_w      = (const float*)d_in[3];
    const float* qkv_b      = (const float*)d_in[4];
    const float* attn_in_w  = (const float*)d_in[5];
    const float* attn_in_b  = (const float*)d_in[6];
    const float* attn_out_w = (const float*)d_in[7];
    const float* attn_out_b = (const float*)d_in[8];
    const float* ln2_g      = (const float*)d_in[9];
    const float* ln2_b      = (const float*)d_in[10];
    const float* r_w1       = (const float*)d_in[11];
    const float* r_b1       = (const float*)d_in[12];
    const float* r_w2       = (const float*)d_in[13];
    const float* r_b2       = (const float*)d_in[14];
    const float* mlp1       = (const float*)d_in[15];
    const float* mlp2       = (const float*)d_in[16];

    float* ws = (float*)d_ws;
    ushort* qkv_hi   = (ushort*)(ws + F_QKV_HI);
    ushort* qkv_lo   = (ushort*)(ws + F_QKV_LO);
    ushort* xn_hi    = (ushort*)(ws + F_XN_HI);
    ushort* xn_lo    = (ushort*)(ws + F_XN_LO);
    float*  h1       = ws + F_H1;
    float*  eout     = ws + F_EOUT;
    float*  qbuf     = ws + F_QBUF;
    float*  kbuf     = ws + F_KBUF;
    float*  vbuf     = ws + F_VBUF;
    ushort* ao_hi    = (ushort*)(ws + F_AO_HI);
    ushort* ao_lo    = (ushort*)(ws + F_AO_LO);
    ushort* xf_hi    = (ushort*)(ws + F_XF_HI);
    ushort* xf_lo    = (ushort*)(ws + F_XF_LO);
    ushort* wqkv_hi  = (ushort*)(ws + F_WQKV_HI);
    ushort* wqkv_lo  = (ushort*)(ws + F_WQKV_LO);
    ushort* wain_hi  = (ushort*)(ws + F_WAIN_HI);
    ushort* wain_lo  = (ushort*)(ws + F_WAIN_LO);
    ushort* waout_hi = (ushort*)(ws + F_WAOUT_HI);
    ushort* waout_lo = (ushort*)(ws + F_WAOUT_LO);
    ushort* wr1_hi   = (ushort*)(ws + F_WR1_HI);
    ushort* wr1_lo   = (ushort*)(ws + F_WR1_LO);
    ushort* expert_in= (ushort*)(ws + F_EXPIN);
    ushort* mlp1t    = (ushort*)(ws + F_MLP1T);
    ushort* mid      = (ushort*)(ws + F_MID);
    ushort* mlp2t    = (ushort*)(ws + F_MLP2T);
    float*  x1       = ws + F_X1;
    float*  xf       = ws + F_XF;
    float*  probs    = ws + F_PROBS;
    int*    inds     = (int*)(ws + F_INDS);
    int*    keep     = (int*)(ws + F_KEEP);
    int*    flat     = (int*)(ws + F_FLAT);

    float* out        = (float*)d_out;
    float* logits_out = out + (size_t)NTOK * DIM;

    // weight splits (fp16 hi + scaled lo)
    split_f32<<<(3145728 / 4 + 255) / 256, 256, 0, stream>>>(qkv_w, wqkv_hi, wqkv_lo, 3145728 / 4);
    split_f32<<<(3145728 / 4 + 255) / 256, 256, 0, stream>>>(attn_in_w, wain_hi, wain_lo, 3145728 / 4);
    split_f32<<<(1048576 / 4 + 255) / 256, 256, 0, stream>>>(attn_out_w, waout_hi, waout_lo, 1048576 / 4);
    split_f32<<<(4194304 / 4 + 255) / 256, 256, 0, stream>>>(r_w1, wr1_hi, wr1_lo, 4194304 / 4);

    // 1. LN1 -> xn hi/lo
    ln_kernel<<<NTOK, 256, 0, stream>>>(x, ln1_g, ln1_b, nullptr, xn_hi, xn_lo);
    // 2. qkv = xn @ qkv_w.T + qkv_b   (split, out hi/lo)
    gemm_ht<true><<<dim3(H3 / 128, NTOK / 128, 1), 256, 0, stream>>>(
        xn_hi, xn_lo, DIM, 0, wqkv_hi, wqkv_lo, DIM, 0, qkv_b, 0,
        nullptr, 0, nullptr, qkv_hi, qkv_lo, H3, 0, DIM, 0, 0);
    // 3. q/k/v in-projections, batched z=3 (split, out fp32)
    gemm_ht<true><<<dim3(DIM / 128, NTOK / 128, 3), 256, 0, stream>>>(
        qkv_hi, qkv_lo, H3, 1024, wain_hi, wain_lo, DIM, 1048576, attn_in_b, 1024,
        nullptr, 0, qbuf, nullptr, nullptr, DIM, 4194304, DIM, 0, 0);
    // 4. attention -> ao hi/lo
    attn_kernel<<<dim3(4, 64), 256, 0, stream>>>(qbuf, kbuf, vbuf, ao_hi, ao_lo);
    // 5. x1 = x + ao @ attn_out_w.T + b  (split, out fp32)
    gemm_ht<true><<<dim3(DIM / 128, NTOK / 128, 1), 256, 0, stream>>>(
        ao_hi, ao_lo, DIM, 0, waout_hi, waout_lo, DIM, 0, attn_out_b, 0,
        x, DIM, x1, nullptr, nullptr, DIM, 0, DIM, 0, 0);
    // 6. LN2 -> xf fp32 + hi/lo
    ln_kernel<<<NTOK, 256, 0, stream>>>(x1, ln2_g, ln2_b, xf, xf_hi, xf_lo);
    // 7. h1 = gelu(xf @ r_w1.T + r_b1)  (split, out fp32)
    gemm_ht<true><<<dim3(HMLP / 128, NTOK / 128, 1), 256, 0, stream>>>(
        xf_hi, xf_lo, DIM, 0, wr1_hi, wr1_lo, DIM, 0, r_b1, 0,
        nullptr, 0, h1, nullptr, nullptr, HMLP, 0, DIM, 1, 0);
    // 8. router logits + top-2 (fp32)
    router2_kernel<<<NTOK, 256, 0, stream>>>(h1, r_w2, r_b2, logits_out, probs, inds);
    // 9. capacity scan
    scan_kernel<<<1, 256, 0, stream>>>(inds, keep, flat);
    // 10. scatter (fp32 xf -> fp16 expert buffers)
    scatter_kernel<<<NTOK * 2, 256, 0, stream>>>(xf, keep, flat, expert_in);
    // 11. expert FFN, fp16 MFMA, H chunked (transpose weights per chunk)
    for (int c = 0; c < HMLP / HCHUNK; c++) {
        transpose_h<<<dim3(32, 32, NEXP), 256, 0, stream>>>(
            mlp1 + (size_t)c * HCHUNK, (long long)DIM * HMLP, HMLP, mlp1t, 1048576, DIM);
        gemm_ht<false><<<dim3(HCHUNK / 128, CAP / 128, NEXP), 256, 0, stream>>>(
            expert_in, nullptr, DIM, 655360, mlp1t, nullptr, DIM, 1048576, nullptr, 0,
            nullptr, 0, nullptr, mid, nullptr, HCHUNK, 655360, DIM, 1, 0);
        transpose_h<<<dim3(32, 32, NEXP), 256, 0, stream>>>(
            mlp2 + (size_t)c * HCHUNK * DIM, (long long)HMLP * DIM, DIM, mlp2t, 1048576, HCHUNK);
        gemm_ht<false><<<dim3(DIM / 128, CAP / 128, NEXP), 256, 0, stream>>>(
            mid, nullptr, HCHUNK, 655360, mlp2t, nullptr, HCHUNK, 1048576, nullptr, 0,
            nullptr, 0, eout, nullptr, nullptr, DIM, 655360, HCHUNK, 0, c > 0);
    }
    // 12. combine + residual
    combine_kernel<<<NTOK, 256, 0, stream>>>(x1, xf, eout, probs, keep, flat, out);
}